// Round 15
// baseline (212.270 us; speedup 1.0000x reference)
//
#include <hip/hip_runtime.h>

typedef __attribute__((ext_vector_type(8))) short bf16x8;
typedef __attribute__((ext_vector_type(4))) short bf16x4;
typedef __attribute__((ext_vector_type(4))) float f32x4;

__device__ __forceinline__ float bf2f(unsigned short u) {
    unsigned int x = ((unsigned int)u) << 16;
    float f;
    __builtin_memcpy(&f, &x, 4);
    return f;
}
__device__ __forceinline__ unsigned short f2bf(float f) {
    unsigned int x;
    __builtin_memcpy(&x, &f, 4);
    x += 0x7FFFu + ((x >> 16) & 1u);
    return (unsigned short)(x >> 16);
}

// Async global->LDS: HW writes lds[base + lane*16]; gptr is per-lane.
#define GLOAD_LDS16(gp, lp)                                      \
    __builtin_amdgcn_global_load_lds(                            \
        (const __attribute__((address_space(1))) void*)(gp),     \
        (__attribute__((address_space(3))) void*)(lp), 16, 0, 0)

// -------------------------------------------------------------------------
// Fused preprocessing, G13-vectorized: 8 elems/thread, float4 x2 loads,
// one 16B bf16x8 store.
// blocks [0,2048):       cast x f32 -> bf16      (4096x1024)
// blocks [2048,3584):    fold_lora attn          (3072x1024)
// blocks [3584,4096):    fold_lora proj          (1024x1024)
__global__ __launch_bounds__(256) void prep(
    const float* __restrict__ x, unsigned short* __restrict__ xb,
    const float* __restrict__ w_attn, const float* __restrict__ la_attn,
    const float* __restrict__ lb_attn, unsigned short* __restrict__ Weff_attn,
    const float* __restrict__ w_proj, const float* __restrict__ la_proj,
    const float* __restrict__ lb_proj, unsigned short* __restrict__ Weff_proj) {
    const int bid = blockIdx.x;
    if (bid < 2048) {
        int i = (bid * 256 + threadIdx.x) * 8;
        float4 v0 = *(const float4*)(x + i);
        float4 v1 = *(const float4*)(x + i + 4);
        bf16x8 o;
        o[0] = (short)f2bf(v0.x); o[1] = (short)f2bf(v0.y);
        o[2] = (short)f2bf(v0.z); o[3] = (short)f2bf(v0.w);
        o[4] = (short)f2bf(v1.x); o[5] = (short)f2bf(v1.y);
        o[6] = (short)f2bf(v1.z); o[7] = (short)f2bf(v1.w);
        *(bf16x8*)(xb + i) = o;
        return;
    }
    const float* W;
    const float* Ain;
    const float* Bin;
    unsigned short* Weff;
    int idx;
    if (bid < 3584) {
        idx = ((bid - 2048) * 256 + threadIdx.x) * 8;
        W = w_attn; Ain = la_attn; Bin = lb_attn; Weff = Weff_attn;
    } else {
        idx = ((bid - 3584) * 256 + threadIdx.x) * 8;
        W = w_proj; Ain = la_proj; Bin = lb_proj; Weff = Weff_proj;
    }
    const int n = idx >> 10;
    const int k = idx & 1023;
    float s[8];
#pragma unroll
    for (int j = 0; j < 8; ++j) s[j] = 0.f;
#pragma unroll
    for (int r = 0; r < 16; ++r) {
        const float bcoef = Bin[n * 16 + r];
        float4 a0 = *(const float4*)(Ain + r * 1024 + k);
        float4 a1 = *(const float4*)(Ain + r * 1024 + k + 4);
        s[0] += bcoef * a0.x; s[1] += bcoef * a0.y;
        s[2] += bcoef * a0.z; s[3] += bcoef * a0.w;
        s[4] += bcoef * a1.x; s[5] += bcoef * a1.y;
        s[6] += bcoef * a1.z; s[7] += bcoef * a1.w;
    }
    float4 w0 = *(const float4*)(W + idx);
    float4 w1 = *(const float4*)(W + idx + 4);
    bf16x8 o;
    o[0] = (short)f2bf(w0.x + 0.0625f * s[0]);
    o[1] = (short)f2bf(w0.y + 0.0625f * s[1]);
    o[2] = (short)f2bf(w0.z + 0.0625f * s[2]);
    o[3] = (short)f2bf(w0.w + 0.0625f * s[3]);
    o[4] = (short)f2bf(w1.x + 0.0625f * s[4]);
    o[5] = (short)f2bf(w1.y + 0.0625f * s[5]);
    o[6] = (short)f2bf(w1.z + 0.0625f * s[6]);
    o[7] = (short)f2bf(w1.w + 0.0625f * s[7]);
    *(bf16x8*)(Weff + idx) = o;
}

// -------------------------------------------------------------------------
// C[M][N] = A[M][K] @ B[N][K]^T + bias[N].  A,B bf16; bias float; fp32 acc.
// 2-phase double-buffer (T3-minimum): stage next K-tile first, compute,
// then one barrier per phase. VSPLIT: V third of qkv written transposed.
template <bool F32OUT, bool VSPLIT>
__global__ __launch_bounds__(256) void gemm_bt_bias(
    const unsigned short* __restrict__ A, const unsigned short* __restrict__ B,
    const float* __restrict__ bias, unsigned short* __restrict__ Cb,
    float* __restrict__ Cf, unsigned short* __restrict__ Vtout,
    int M, int N, int K) {
    __shared__ unsigned short sA0[128 * 32], sA1[128 * 32];
    __shared__ unsigned short sB0[128 * 32], sB1[128 * 32];
    const int tid = threadIdx.x;
    const int wave = tid >> 6, lane = tid & 63;
    const int quad = lane >> 4, l16 = lane & 15;
    const int m0 = blockIdx.y * 128, n0 = blockIdx.x * 128;
    const int wm = (wave & 1) * 64, wn = (wave >> 1) * 64;

    const int srow = wave * 32 + (lane >> 2);
    const int scol = (lane & 3) * 8;
    const unsigned short* Ag = A + (size_t)(m0 + srow) * K + scol;
    const unsigned short* Bg = B + (size_t)(n0 + srow) * K + scol;
    const int woff = wave * 1024;
    const size_t kjump = (size_t)16 * K;

    f32x4 acc[4][4];
#pragma unroll
    for (int i = 0; i < 4; ++i)
#pragma unroll
        for (int j = 0; j < 4; ++j) acc[i][j] = (f32x4){0.f, 0.f, 0.f, 0.f};

    auto stage = [&](unsigned short* dA, unsigned short* dB, int k) {
        GLOAD_LDS16(Ag + k, dA + woff);
        GLOAD_LDS16(Ag + k + kjump, dA + woff + 512);
        GLOAD_LDS16(Bg + k, dB + woff);
        GLOAD_LDS16(Bg + k + kjump, dB + woff + 512);
    };
    auto compute = [&](const unsigned short* cA, const unsigned short* cB) {
        bf16x8 af[4], bfr[4];
#pragma unroll
        for (int mi = 0; mi < 4; ++mi)
            af[mi] = *(const bf16x8*)&cA[(wm + mi * 16 + l16) * 32 + quad * 8];
#pragma unroll
        for (int ni = 0; ni < 4; ++ni)
            bfr[ni] = *(const bf16x8*)&cB[(wn + ni * 16 + l16) * 32 + quad * 8];
#pragma unroll
        for (int mi = 0; mi < 4; ++mi)
#pragma unroll
            for (int ni = 0; ni < 4; ++ni)
                acc[mi][ni] = __builtin_amdgcn_mfma_f32_16x16x32_bf16(
                    af[mi], bfr[ni], acc[mi][ni], 0, 0, 0);
    };

    stage(sA0, sB0, 0);
    __syncthreads();  // tile 0 resident (vmcnt(0) drained by barrier)
    for (int k0 = 0; k0 < K; k0 += 64) {
        if (k0 + 32 < K) stage(sA1, sB1, k0 + 32);  // in flight during MFMA
        compute(sA0, sB0);
        __syncthreads();  // next tile resident; buf0 reads done
        if (k0 + 64 < K) stage(sA0, sB0, k0 + 64);
        compute(sA1, sB1);
        __syncthreads();
    }

    float bv[4];
#pragma unroll
    for (int ni = 0; ni < 4; ++ni) bv[ni] = bias[n0 + wn + ni * 16 + l16];

    if (VSPLIT && n0 >= 2048) {
#pragma unroll
        for (int ni = 0; ni < 4; ++ni) {
            const int hcol = n0 + wn + ni * 16 + l16 - 2048;
#pragma unroll
            for (int mi = 0; mi < 4; ++mi) {
                const int rowtop = m0 + wm + mi * 16 + quad * 4;
                const int bb = rowtop >> 11;
                const int t = rowtop & 2047;
                bf16x4 pk;
#pragma unroll
                for (int r = 0; r < 4; ++r)
                    pk[r] = (short)f2bf(acc[mi][ni][r] + bv[ni]);
                *(bf16x4*)(Vtout +
                           ((size_t)((bb * 16 + (hcol >> 6)) * 64 + (hcol & 63))) *
                               2048 +
                           t) = pk;
            }
        }
        return;
    }

#pragma unroll
    for (int mi = 0; mi < 4; ++mi)
#pragma unroll
        for (int ni = 0; ni < 4; ++ni)
#pragma unroll
            for (int r = 0; r < 4; ++r) {
                int row = m0 + wm + mi * 16 + quad * 4 + r;
                int col = n0 + wn + ni * 16 + l16;
                float val = acc[mi][ni][r] + bv[ni];
                if (F32OUT)
                    Cf[(size_t)row * N + col] = val;
                else
                    Cb[(size_t)row * N + col] = f2bf(val);
            }
}

// -------------------------------------------------------------------------
// BM=64 variant for the proj GEMM, same 2-phase double-buffer.
__global__ __launch_bounds__(256) void gemm_bt_bias64(
    const unsigned short* __restrict__ A, const unsigned short* __restrict__ B,
    const float* __restrict__ bias, float* __restrict__ Cf,
    int M, int N, int K) {
    __shared__ unsigned short sA0[64 * 32], sA1[64 * 32];
    __shared__ unsigned short sB0[128 * 32], sB1[128 * 32];
    const int tid = threadIdx.x;
    const int wave = tid >> 6, lane = tid & 63;
    const int quad = lane >> 4, l16 = lane & 15;
    const int m0 = blockIdx.y * 64, n0 = blockIdx.x * 128;
    const int wn = wave * 32;

    const int srowA = wave * 16 + (lane >> 2);
    const int srowB = wave * 32 + (lane >> 2);
    const int scol = (lane & 3) * 8;
    const unsigned short* Ag = A + (size_t)(m0 + srowA) * K + scol;
    const unsigned short* Bg = B + (size_t)(n0 + srowB) * K + scol;
    const int woffA = wave * 512, woffB = wave * 1024;
    const size_t kjump = (size_t)16 * K;

    f32x4 acc[4][2];
#pragma unroll
    for (int i = 0; i < 4; ++i)
#pragma unroll
        for (int j = 0; j < 2; ++j) acc[i][j] = (f32x4){0.f, 0.f, 0.f, 0.f};

    auto stage = [&](unsigned short* dA, unsigned short* dB, int k) {
        GLOAD_LDS16(Ag + k, dA + woffA);
        GLOAD_LDS16(Bg + k, dB + woffB);
        GLOAD_LDS16(Bg + k + kjump, dB + woffB + 512);
    };
    auto compute = [&](const unsigned short* cA, const unsigned short* cB) {
        bf16x8 af[4], bfr[2];
#pragma unroll
        for (int mi = 0; mi < 4; ++mi)
            af[mi] = *(const bf16x8*)&cA[(mi * 16 + l16) * 32 + quad * 8];
#pragma unroll
        for (int ni = 0; ni < 2; ++ni)
            bfr[ni] = *(const bf16x8*)&cB[(wn + ni * 16 + l16) * 32 + quad * 8];
#pragma unroll
        for (int mi = 0; mi < 4; ++mi)
#pragma unroll
            for (int ni = 0; ni < 2; ++ni)
                acc[mi][ni] = __builtin_amdgcn_mfma_f32_16x16x32_bf16(
                    af[mi], bfr[ni], acc[mi][ni], 0, 0, 0);
    };

    stage(sA0, sB0, 0);
    __syncthreads();
    for (int k0 = 0; k0 < K; k0 += 64) {
        if (k0 + 32 < K) stage(sA1, sB1, k0 + 32);
        compute(sA0, sB0);
        __syncthreads();
        if (k0 + 64 < K) stage(sA0, sB0, k0 + 64);
        compute(sA1, sB1);
        __syncthreads();
    }

    float bv[2];
#pragma unroll
    for (int ni = 0; ni < 2; ++ni) bv[ni] = bias[n0 + wn + ni * 16 + l16];
#pragma unroll
    for (int mi = 0; mi < 4; ++mi)
#pragma unroll
        for (int ni = 0; ni < 2; ++ni)
#pragma unroll
            for (int r = 0; r < 4; ++r) {
                int row = m0 + mi * 16 + quad * 4 + r;
                int col = n0 + wn + ni * 16 + l16;
                Cf[(size_t)row * N + col] = acc[mi][ni][r] + bv[ni];
            }
}

// -------------------------------------------------------------------------
// Flash attention v13: 32-row q-blocks + 2x oversubscription.
// v12/v11 established attn is critical-path-time bound with occupancy
// decay (grid==residency: freed slots stay empty, avg occupancy 24%).
// Inverse of v10's failure: blocks now own 32 q-rows (wave = 16q x 32kv,
// m-loop gone -> ~40% lighter tiles -> shorter critical-path TIME), grid
// doubles to 2048 blocks = 2x oversubscription so the HW scheduler refills
// freed slots (longest blocks j=63 dispatch first). No partial outputs:
// causal kv range is self-contained per q-block (ntiles = j/2+1).
// K/V dbuf, permuted-K in-register softmax retained. T5 setprio around the
// PV MFMA cluster (m191: +4-7% in this independent-block regime).
__global__ __launch_bounds__(256, 4) void attn_kernel(
    const unsigned short* __restrict__ qkv,  // [4096][3072] bf16
    const unsigned short* __restrict__ Vt,   // [32][64][2048] bf16
    unsigned short* __restrict__ y) {        // [4096][1024] bf16
    const int b = blockIdx.z, h = blockIdx.y;
    const int bh = b * 16 + h;
    const int j = 63 - (int)blockIdx.x;  // longest blocks dispatch first
    const int w = threadIdx.x >> 6, lane = threadIdx.x & 63;
    const int quad = lane >> 4, l16 = lane & 15;
    const int qh = w & 1, kvh = w >> 1;
    const int q0 = j * 32 + qh * 16;     // wave's 16 q-rows
    const int ntiles = (j >> 1) + 1;

    __shared__ __align__(16) char smem[2 * 18432 + 512];
    unsigned short* bufA = (unsigned short*)smem;            // K[64][72]+V[64][72]
    unsigned short* bufB = (unsigned short*)(smem + 18432);
    float* sO = (float*)smem;                // reuse at end: [2][64][20]
    float* sD = (float*)(smem + 2 * 18432);  // [4][16] denominators

    const unsigned short* Qb = qkv + (size_t)(b * 2048) * 3072 + h * 64;
    const unsigned short* Kg = Qb + 1024;
    const unsigned short* Vg = Vt + (size_t)(bh * 64) * 2048;

    const int rlo = threadIdx.x >> 3;      // 0..31 (staging role)
    const int c8 = (threadIdx.x & 7) * 8;  // 0..56

    bf16x8 qf0 = *(const bf16x8*)(Qb + (size_t)(q0 + l16) * 3072 + quad * 8);
    bf16x8 qf1 = *(const bf16x8*)(Qb + (size_t)(q0 + l16) * 3072 + 32 + quad * 8);

    // Permuted K-row base: mfma f reads kv row krow0 + 4f.
    const int krow0 = kvh * 32 + 8 * (l16 >> 2) + (l16 & 3);

    f32x4 o[4];
    float lacc = 0.f;
#pragma unroll
    for (int nt = 0; nt < 4; ++nt) o[nt] = (f32x4){0.f, 0.f, 0.f, 0.f};

    const float csc = 0.125f * 1.44269504088896340736f;  // (1/sqrt 64)*log2(e)

    // Prologue: tile 0 into bufA.
    bf16x8 kr0 = *(const bf16x8*)(Kg + (size_t)rlo * 3072 + c8);
    bf16x8 kr1 = *(const bf16x8*)(Kg + (size_t)(rlo + 32) * 3072 + c8);
    bf16x8 vr0 = *(const bf16x8*)(Vg + (size_t)rlo * 2048 + c8);
    bf16x8 vr1 = *(const bf16x8*)(Vg + (size_t)(rlo + 32) * 2048 + c8);
    {
        unsigned short* sK = bufA;
        unsigned short* sV = bufA + 64 * 72;
        *(bf16x8*)&sK[rlo * 72 + c8] = kr0;
        *(bf16x8*)&sK[(rlo + 32) * 72 + c8] = kr1;
        *(bf16x8*)&sV[rlo * 72 + c8] = vr0;
        *(bf16x8*)&sV[(rlo + 32) * 72 + c8] = vr1;
    }
    __syncthreads();  // tile 0 resident

    unsigned short* bcur = bufA;
    unsigned short* bnxt = bufB;

    for (int it = 0; it < ntiles; ++it) {
        const bool pf = (it + 1 < ntiles);
        if (pf) {  // issue next tile's loads NOW; latency hides under compute
            const int nx = (it + 1) * 64;
            kr0 = *(const bf16x8*)(Kg + (size_t)(nx + rlo) * 3072 + c8);
            kr1 = *(const bf16x8*)(Kg + (size_t)(nx + rlo + 32) * 3072 + c8);
            vr0 = *(const bf16x8*)(Vg + (size_t)rlo * 2048 + nx + c8);
            vr1 = *(const bf16x8*)(Vg + (size_t)(rlo + 32) * 2048 + nx + c8);
        }

        const unsigned short* sK = bcur;
        const unsigned short* sV = bcur + 64 * 72;

        // K A-fragments (permuted rows): ka[f][half] covers d half 0/1.
        bf16x8 ka[2][2];
#pragma unroll
        for (int f = 0; f < 2; ++f) {
            ka[f][0] = *(const bf16x8*)&sK[(krow0 + 4 * f) * 72 + quad * 8];
            ka[f][1] = *(const bf16x8*)&sK[(krow0 + 4 * f) * 72 + 32 + quad * 8];
        }
        // V B-fragments: vb[nt] = Vt[d=nt*16+l16][kv = kvh*32 + quad*8 + j]
        bf16x8 vb[4];
#pragma unroll
        for (int nt = 0; nt < 4; ++nt)
            vb[nt] = *(const bf16x8*)&sV[(nt * 16 + l16) * 72 + kvh * 32 + quad * 8];

        const int kv0 = it * 64;
        const bool diag = (it == ntiles - 1);  // only last tile crosses diag
        const int qa = q0 + l16;               // absolute q for this thread
        unsigned int pw[4];
        float lsum = 0.f;
#pragma unroll
        for (int f = 0; f < 2; ++f) {
            f32x4 S = (f32x4){0.f, 0.f, 0.f, 0.f};
            S = __builtin_amdgcn_mfma_f32_16x16x32_bf16(ka[f][0], qf0, S, 0, 0, 0);
            S = __builtin_amdgcn_mfma_f32_16x16x32_bf16(ka[f][1], qf1, S, 0, 0, 0);
            float p0, p1, p2, p3;
            {
                float sv = S[0] * csc;
                asm("v_exp_f32 %0, %1" : "=v"(p0) : "v"(sv));
                sv = S[1] * csc;
                asm("v_exp_f32 %0, %1" : "=v"(p1) : "v"(sv));
                sv = S[2] * csc;
                asm("v_exp_f32 %0, %1" : "=v"(p2) : "v"(sv));
                sv = S[3] * csc;
                asm("v_exp_f32 %0, %1" : "=v"(p3) : "v"(sv));
            }
            if (diag) {  // kv_abs = kv0 + kvh*32 + 8*quad + 4f + r
                int kvb = kv0 + kvh * 32 + 8 * quad + 4 * f;
                p0 = (kvb + 0 <= qa) ? p0 : 0.f;
                p1 = (kvb + 1 <= qa) ? p1 : 0.f;
                p2 = (kvb + 2 <= qa) ? p2 : 0.f;
                p3 = (kvb + 3 <= qa) ? p3 : 0.f;
            }
            lsum += (p0 + p1) + (p2 + p3);
            asm("v_cvt_pk_bf16_f32 %0, %1, %2" : "=v"(pw[f * 2 + 0]) : "v"(p0), "v"(p1));
            asm("v_cvt_pk_bf16_f32 %0, %1, %2" : "=v"(pw[f * 2 + 1]) : "v"(p2), "v"(p3));
        }
        lacc += lsum;
        union {
            unsigned int u[4];
            bf16x8 v;
        } pa;
        pa.u[0] = pw[0]; pa.u[1] = pw[1]; pa.u[2] = pw[2]; pa.u[3] = pw[3];
        __builtin_amdgcn_s_setprio(1);  // T5: favor the MFMA cluster
#pragma unroll
        for (int nt = 0; nt < 4; ++nt)
            o[nt] = __builtin_amdgcn_mfma_f32_16x16x32_bf16(
                pa.v, vb[nt], o[nt], 0, 0, 0);
        __builtin_amdgcn_s_setprio(0);

        if (pf) {  // write prefetched tile to the other buffer (vmcnt waits here)
            unsigned short* dK = bnxt;
            unsigned short* dV = bnxt + 64 * 72;
            *(bf16x8*)&dK[rlo * 72 + c8] = kr0;
            *(bf16x8*)&dK[(rlo + 32) * 72 + c8] = kr1;
            *(bf16x8*)&dV[rlo * 72 + c8] = vr0;
            *(bf16x8*)&dV[(rlo + 32) * 72 + c8] = vr1;
        }
        __syncthreads();  // single barrier: RAW for bnxt, WAR for bcur
        unsigned short* t = bcur; bcur = bnxt; bnxt = t;
    }

    // Per-wave denom: sum over quads (kv within the wave's half).
    lacc += __shfl_xor(lacc, 16);
    lacc += __shfl_xor(lacc, 32);

    // Last loop barrier separates main-loop LDS use from reuse below.
    if (kvh == 1) {  // kv-half 1 waves publish partial o: [d 64][q 16 + pad]
        float* dst = sO + qh * (64 * 20);
#pragma unroll
        for (int nt = 0; nt < 4; ++nt)
            *(f32x4*)&dst[(nt * 16 + l16) * 20 + quad * 4] = o[nt];
    }
    if (lane < 16) sD[w * 16 + l16] = lacc;
    __syncthreads();
    if (kvh == 0) {  // kv-half 0 waves combine and write output
        const float* src = sO + qh * (64 * 20);
        unsigned short* yb = y + (size_t)(b * 2048) * 1024 + h * 64;
        float dfull = lacc + sD[(w + 2) * 16 + l16];
        float lt[4];
#pragma unroll
        for (int r = 0; r < 4; ++r) lt[r] = __shfl(dfull, quad * 4 + r);
#pragma unroll
        for (int nt = 0; nt < 4; ++nt) {
            f32x4 part = *(const f32x4*)&src[(nt * 16 + l16) * 20 + quad * 4];
#pragma unroll
            for (int r = 0; r < 4; ++r)
                yb[(size_t)(q0 + quad * 4 + r) * 1024 + nt * 16 + l16] =
                    f2bf((o[nt][r] + part[r]) / lt[r]);
        }
    }
}

// -------------------------------------------------------------------------
extern "C" void kernel_launch(void* const* d_in, const int* in_sizes, int n_in,
                              void* d_out, int out_size, void* d_ws, size_t ws_size,
                              hipStream_t stream) {
    const float* x       = (const float*)d_in[0];
    const float* w_attn  = (const float*)d_in[1];
    const float* b_attn  = (const float*)d_in[2];
    const float* la_attn = (const float*)d_in[3];
    const float* lb_attn = (const float*)d_in[4];
    const float* w_proj  = (const float*)d_in[5];
    const float* b_proj  = (const float*)d_in[6];
    const float* la_proj = (const float*)d_in[7];
    const float* lb_proj = (const float*)d_in[8];
    float* out = (float*)d_out;

    char* w = (char*)d_ws;
    unsigned short* xb        = (unsigned short*)w; w += (size_t)4096 * 1024 * 2;
    unsigned short* Weff_attn = (unsigned short*)w; w += (size_t)3072 * 1024 * 2;
    unsigned short* Weff_proj = (unsigned short*)w; w += (size_t)1024 * 1024 * 2;
    unsigned short* qkv       = (unsigned short*)w; w += (size_t)4096 * 3072 * 2;
    unsigned short* Vt        = (unsigned short*)w; w += (size_t)32 * 64 * 2048 * 2;
    unsigned short* y         = (unsigned short*)w; w += (size_t)4096 * 1024 * 2;

    prep<<<4096, 256, 0, stream>>>(x, xb, w_attn, la_attn, lb_attn, Weff_attn,
                                   w_proj, la_proj, lb_proj, Weff_proj);
    gemm_bt_bias<false, true><<<dim3(24, 32), 256, 0, stream>>>(
        xb, Weff_attn, b_attn, qkv, (float*)nullptr, Vt, 4096, 3072, 1024);
    attn_kernel<<<dim3(64, 16, 2), 256, 0, stream>>>(qkv, Vt, y);
    gemm_bt_bias64<<<dim3(8, 64), 256, 0, stream>>>(
        y, Weff_proj, b_proj, out, 4096, 1024, 1024);
}

// Round 16
// 186.961 us; speedup vs baseline: 1.1354x; 1.1354x over previous
//
#include <hip/hip_runtime.h>

typedef __attribute__((ext_vector_type(8))) short bf16x8;
typedef __attribute__((ext_vector_type(4))) short bf16x4;
typedef __attribute__((ext_vector_type(4))) float f32x4;

__device__ __forceinline__ float bf2f(unsigned short u) {
    unsigned int x = ((unsigned int)u) << 16;
    float f;
    __builtin_memcpy(&f, &x, 4);
    return f;
}
__device__ __forceinline__ unsigned short f2bf(float f) {
    unsigned int x;
    __builtin_memcpy(&x, &f, 4);
    x += 0x7FFFu + ((x >> 16) & 1u);
    return (unsigned short)(x >> 16);
}

// Async global->LDS: HW writes lds[base + lane*16]; gptr is per-lane.
#define GLOAD_LDS16(gp, lp)                                      \
    __builtin_amdgcn_global_load_lds(                            \
        (const __attribute__((address_space(1))) void*)(gp),     \
        (__attribute__((address_space(3))) void*)(lp), 16, 0, 0)

// -------------------------------------------------------------------------
// Fused preprocessing, G13-vectorized: 8 elems/thread, float4 x2 loads,
// one 16B bf16x8 store.
// blocks [0,2048):       cast x f32 -> bf16      (4096x1024)
// blocks [2048,3584):    fold_lora attn          (3072x1024)
// blocks [3584,4096):    fold_lora proj          (1024x1024)
__global__ __launch_bounds__(256) void prep(
    const float* __restrict__ x, unsigned short* __restrict__ xb,
    const float* __restrict__ w_attn, const float* __restrict__ la_attn,
    const float* __restrict__ lb_attn, unsigned short* __restrict__ Weff_attn,
    const float* __restrict__ w_proj, const float* __restrict__ la_proj,
    const float* __restrict__ lb_proj, unsigned short* __restrict__ Weff_proj) {
    const int bid = blockIdx.x;
    if (bid < 2048) {
        int i = (bid * 256 + threadIdx.x) * 8;
        float4 v0 = *(const float4*)(x + i);
        float4 v1 = *(const float4*)(x + i + 4);
        bf16x8 o;
        o[0] = (short)f2bf(v0.x); o[1] = (short)f2bf(v0.y);
        o[2] = (short)f2bf(v0.z); o[3] = (short)f2bf(v0.w);
        o[4] = (short)f2bf(v1.x); o[5] = (short)f2bf(v1.y);
        o[6] = (short)f2bf(v1.z); o[7] = (short)f2bf(v1.w);
        *(bf16x8*)(xb + i) = o;
        return;
    }
    const float* W;
    const float* Ain;
    const float* Bin;
    unsigned short* Weff;
    int idx;
    if (bid < 3584) {
        idx = ((bid - 2048) * 256 + threadIdx.x) * 8;
        W = w_attn; Ain = la_attn; Bin = lb_attn; Weff = Weff_attn;
    } else {
        idx = ((bid - 3584) * 256 + threadIdx.x) * 8;
        W = w_proj; Ain = la_proj; Bin = lb_proj; Weff = Weff_proj;
    }
    const int n = idx >> 10;
    const int k = idx & 1023;
    float s[8];
#pragma unroll
    for (int j = 0; j < 8; ++j) s[j] = 0.f;
#pragma unroll
    for (int r = 0; r < 16; ++r) {
        const float bcoef = Bin[n * 16 + r];
        float4 a0 = *(const float4*)(Ain + r * 1024 + k);
        float4 a1 = *(const float4*)(Ain + r * 1024 + k + 4);
        s[0] += bcoef * a0.x; s[1] += bcoef * a0.y;
        s[2] += bcoef * a0.z; s[3] += bcoef * a0.w;
        s[4] += bcoef * a1.x; s[5] += bcoef * a1.y;
        s[6] += bcoef * a1.z; s[7] += bcoef * a1.w;
    }
    float4 w0 = *(const float4*)(W + idx);
    float4 w1 = *(const float4*)(W + idx + 4);
    bf16x8 o;
    o[0] = (short)f2bf(w0.x + 0.0625f * s[0]);
    o[1] = (short)f2bf(w0.y + 0.0625f * s[1]);
    o[2] = (short)f2bf(w0.z + 0.0625f * s[2]);
    o[3] = (short)f2bf(w0.w + 0.0625f * s[3]);
    o[4] = (short)f2bf(w1.x + 0.0625f * s[4]);
    o[5] = (short)f2bf(w1.y + 0.0625f * s[5]);
    o[6] = (short)f2bf(w1.z + 0.0625f * s[6]);
    o[7] = (short)f2bf(w1.w + 0.0625f * s[7]);
    *(bf16x8*)(Weff + idx) = o;
}

// -------------------------------------------------------------------------
// C[M][N] = A[M][K] @ B[N][K]^T + bias[N].  A,B bf16; bias float; fp32 acc.
// 2-phase double-buffer (T3-minimum): stage next K-tile first, compute,
// then one barrier per phase. VSPLIT: V third of qkv written transposed.
template <bool F32OUT, bool VSPLIT>
__global__ __launch_bounds__(256) void gemm_bt_bias(
    const unsigned short* __restrict__ A, const unsigned short* __restrict__ B,
    const float* __restrict__ bias, unsigned short* __restrict__ Cb,
    float* __restrict__ Cf, unsigned short* __restrict__ Vtout,
    int M, int N, int K) {
    __shared__ unsigned short sA0[128 * 32], sA1[128 * 32];
    __shared__ unsigned short sB0[128 * 32], sB1[128 * 32];
    const int tid = threadIdx.x;
    const int wave = tid >> 6, lane = tid & 63;
    const int quad = lane >> 4, l16 = lane & 15;
    const int m0 = blockIdx.y * 128, n0 = blockIdx.x * 128;
    const int wm = (wave & 1) * 64, wn = (wave >> 1) * 64;

    const int srow = wave * 32 + (lane >> 2);
    const int scol = (lane & 3) * 8;
    const unsigned short* Ag = A + (size_t)(m0 + srow) * K + scol;
    const unsigned short* Bg = B + (size_t)(n0 + srow) * K + scol;
    const int woff = wave * 1024;
    const size_t kjump = (size_t)16 * K;

    f32x4 acc[4][4];
#pragma unroll
    for (int i = 0; i < 4; ++i)
#pragma unroll
        for (int j = 0; j < 4; ++j) acc[i][j] = (f32x4){0.f, 0.f, 0.f, 0.f};

    auto stage = [&](unsigned short* dA, unsigned short* dB, int k) {
        GLOAD_LDS16(Ag + k, dA + woff);
        GLOAD_LDS16(Ag + k + kjump, dA + woff + 512);
        GLOAD_LDS16(Bg + k, dB + woff);
        GLOAD_LDS16(Bg + k + kjump, dB + woff + 512);
    };
    auto compute = [&](const unsigned short* cA, const unsigned short* cB) {
        bf16x8 af[4], bfr[4];
#pragma unroll
        for (int mi = 0; mi < 4; ++mi)
            af[mi] = *(const bf16x8*)&cA[(wm + mi * 16 + l16) * 32 + quad * 8];
#pragma unroll
        for (int ni = 0; ni < 4; ++ni)
            bfr[ni] = *(const bf16x8*)&cB[(wn + ni * 16 + l16) * 32 + quad * 8];
#pragma unroll
        for (int mi = 0; mi < 4; ++mi)
#pragma unroll
            for (int ni = 0; ni < 4; ++ni)
                acc[mi][ni] = __builtin_amdgcn_mfma_f32_16x16x32_bf16(
                    af[mi], bfr[ni], acc[mi][ni], 0, 0, 0);
    };

    stage(sA0, sB0, 0);
    __syncthreads();  // tile 0 resident (vmcnt(0) drained by barrier)
    for (int k0 = 0; k0 < K; k0 += 64) {
        if (k0 + 32 < K) stage(sA1, sB1, k0 + 32);  // in flight during MFMA
        compute(sA0, sB0);
        __syncthreads();  // next tile resident; buf0 reads done
        if (k0 + 64 < K) stage(sA0, sB0, k0 + 64);
        compute(sA1, sB1);
        __syncthreads();
    }

    float bv[4];
#pragma unroll
    for (int ni = 0; ni < 4; ++ni) bv[ni] = bias[n0 + wn + ni * 16 + l16];

    if (VSPLIT && n0 >= 2048) {
#pragma unroll
        for (int ni = 0; ni < 4; ++ni) {
            const int hcol = n0 + wn + ni * 16 + l16 - 2048;
#pragma unroll
            for (int mi = 0; mi < 4; ++mi) {
                const int rowtop = m0 + wm + mi * 16 + quad * 4;
                const int bb = rowtop >> 11;
                const int t = rowtop & 2047;
                bf16x4 pk;
#pragma unroll
                for (int r = 0; r < 4; ++r)
                    pk[r] = (short)f2bf(acc[mi][ni][r] + bv[ni]);
                *(bf16x4*)(Vtout +
                           ((size_t)((bb * 16 + (hcol >> 6)) * 64 + (hcol & 63))) *
                               2048 +
                           t) = pk;
            }
        }
        return;
    }

#pragma unroll
    for (int mi = 0; mi < 4; ++mi)
#pragma unroll
        for (int ni = 0; ni < 4; ++ni)
#pragma unroll
            for (int r = 0; r < 4; ++r) {
                int row = m0 + wm + mi * 16 + quad * 4 + r;
                int col = n0 + wn + ni * 16 + l16;
                float val = acc[mi][ni][r] + bv[ni];
                if (F32OUT)
                    Cf[(size_t)row * N + col] = val;
                else
                    Cb[(size_t)row * N + col] = f2bf(val);
            }
}

// -------------------------------------------------------------------------
// BM=64 variant for the proj GEMM, same 2-phase double-buffer.
__global__ __launch_bounds__(256) void gemm_bt_bias64(
    const unsigned short* __restrict__ A, const unsigned short* __restrict__ B,
    const float* __restrict__ bias, float* __restrict__ Cf,
    int M, int N, int K) {
    __shared__ unsigned short sA0[64 * 32], sA1[64 * 32];
    __shared__ unsigned short sB0[128 * 32], sB1[128 * 32];
    const int tid = threadIdx.x;
    const int wave = tid >> 6, lane = tid & 63;
    const int quad = lane >> 4, l16 = lane & 15;
    const int m0 = blockIdx.y * 64, n0 = blockIdx.x * 128;
    const int wn = wave * 32;

    const int srowA = wave * 16 + (lane >> 2);
    const int srowB = wave * 32 + (lane >> 2);
    const int scol = (lane & 3) * 8;
    const unsigned short* Ag = A + (size_t)(m0 + srowA) * K + scol;
    const unsigned short* Bg = B + (size_t)(n0 + srowB) * K + scol;
    const int woffA = wave * 512, woffB = wave * 1024;
    const size_t kjump = (size_t)16 * K;

    f32x4 acc[4][2];
#pragma unroll
    for (int i = 0; i < 4; ++i)
#pragma unroll
        for (int j = 0; j < 2; ++j) acc[i][j] = (f32x4){0.f, 0.f, 0.f, 0.f};

    auto stage = [&](unsigned short* dA, unsigned short* dB, int k) {
        GLOAD_LDS16(Ag + k, dA + woffA);
        GLOAD_LDS16(Bg + k, dB + woffB);
        GLOAD_LDS16(Bg + k + kjump, dB + woffB + 512);
    };
    auto compute = [&](const unsigned short* cA, const unsigned short* cB) {
        bf16x8 af[4], bfr[2];
#pragma unroll
        for (int mi = 0; mi < 4; ++mi)
            af[mi] = *(const bf16x8*)&cA[(mi * 16 + l16) * 32 + quad * 8];
#pragma unroll
        for (int ni = 0; ni < 2; ++ni)
            bfr[ni] = *(const bf16x8*)&cB[(wn + ni * 16 + l16) * 32 + quad * 8];
#pragma unroll
        for (int mi = 0; mi < 4; ++mi)
#pragma unroll
            for (int ni = 0; ni < 2; ++ni)
                acc[mi][ni] = __builtin_amdgcn_mfma_f32_16x16x32_bf16(
                    af[mi], bfr[ni], acc[mi][ni], 0, 0, 0);
    };

    stage(sA0, sB0, 0);
    __syncthreads();
    for (int k0 = 0; k0 < K; k0 += 64) {
        if (k0 + 32 < K) stage(sA1, sB1, k0 + 32);
        compute(sA0, sB0);
        __syncthreads();
        if (k0 + 64 < K) stage(sA0, sB0, k0 + 64);
        compute(sA1, sB1);
        __syncthreads();
    }

    float bv[2];
#pragma unroll
    for (int ni = 0; ni < 2; ++ni) bv[ni] = bias[n0 + wn + ni * 16 + l16];
#pragma unroll
    for (int mi = 0; mi < 4; ++mi)
#pragma unroll
        for (int ni = 0; ni < 2; ++ni)
#pragma unroll
            for (int r = 0; r < 4; ++r) {
                int row = m0 + mi * 16 + quad * 4 + r;
                int col = n0 + wn + ni * 16 + l16;
                Cf[(size_t)row * N + col] = acc[mi][ni][r] + bv[ni];
            }
}

// -------------------------------------------------------------------------
// Flash attention v12 (best known): wave = (q-half, kv-half) partition +
// K/V LDS double-buffer, one barrier per tile. Permuted-K in-register
// softmax (swapped QK^T + cvt_pk feeds PV A-fragment directly, no sP).
// Ledger: DS-op cut (v11) +7%; barrier cut (v12) 0; lighter tiles (v13)
// -55%; heavier tiles (v10) -18%; split-KV -35% -- this is the plateau
// configuration. Residual cost = qblk=31 block's 32-tile serial chain.
__global__ __launch_bounds__(256, 4) void attn_kernel(
    const unsigned short* __restrict__ qkv,  // [4096][3072] bf16
    const unsigned short* __restrict__ Vt,   // [32][64][2048] bf16
    unsigned short* __restrict__ y) {        // [4096][1024] bf16
    const int b = blockIdx.z, h = blockIdx.y;
    const int bh = b * 16 + h;
    const int qblk = (int)blockIdx.x ^ (((bh >> 3) & 1) ? 31 : 0);
    const int w = threadIdx.x >> 6, lane = threadIdx.x & 63;
    const int quad = lane >> 4, l16 = lane & 15;
    const int qh = w & 1, kvh = w >> 1;
    const int q0 = qblk * 64 + qh * 32;  // wave's q base (2 frags of 16)
    const int ntiles = qblk + 1;

    __shared__ __align__(16) char smem[2 * 18432 + 512];
    unsigned short* bufA = (unsigned short*)smem;            // K[64][72]+V[64][72]
    unsigned short* bufB = (unsigned short*)(smem + 18432);
    float* sO = (float*)smem;                 // reuse at end: [2][64][36]
    float* sD = (float*)(smem + 2 * 18432);   // [4][32] denominators

    const unsigned short* Qb = qkv + (size_t)(b * 2048) * 3072 + h * 64;
    const unsigned short* Kg = Qb + 1024;
    const unsigned short* Vg = Vt + (size_t)(bh * 64) * 2048;

    const int rlo = threadIdx.x >> 3;      // 0..31 (staging role)
    const int c8 = (threadIdx.x & 7) * 8;  // 0..56

    bf16x8 qf[2][2];
#pragma unroll
    for (int m = 0; m < 2; ++m) {
        qf[m][0] = *(const bf16x8*)(Qb + (size_t)(q0 + m * 16 + l16) * 3072 + quad * 8);
        qf[m][1] = *(const bf16x8*)(Qb + (size_t)(q0 + m * 16 + l16) * 3072 + 32 + quad * 8);
    }

    // Permuted K-row base: mfma f reads kv row krow0 + 4f.
    const int krow0 = kvh * 32 + 8 * (l16 >> 2) + (l16 & 3);

    f32x4 o[2][4];
    float lacc[2] = {0.f, 0.f};
#pragma unroll
    for (int m = 0; m < 2; ++m)
#pragma unroll
        for (int nt = 0; nt < 4; ++nt) o[m][nt] = (f32x4){0.f, 0.f, 0.f, 0.f};

    const float csc = 0.125f * 1.44269504088896340736f;  // (1/sqrt 64)*log2(e)

    // Prologue: tile 0 into bufA.
    bf16x8 kr0 = *(const bf16x8*)(Kg + (size_t)rlo * 3072 + c8);
    bf16x8 kr1 = *(const bf16x8*)(Kg + (size_t)(rlo + 32) * 3072 + c8);
    bf16x8 vr0 = *(const bf16x8*)(Vg + (size_t)rlo * 2048 + c8);
    bf16x8 vr1 = *(const bf16x8*)(Vg + (size_t)(rlo + 32) * 2048 + c8);
    {
        unsigned short* sK = bufA;
        unsigned short* sV = bufA + 64 * 72;
        *(bf16x8*)&sK[rlo * 72 + c8] = kr0;
        *(bf16x8*)&sK[(rlo + 32) * 72 + c8] = kr1;
        *(bf16x8*)&sV[rlo * 72 + c8] = vr0;
        *(bf16x8*)&sV[(rlo + 32) * 72 + c8] = vr1;
    }
    __syncthreads();  // tile 0 resident

    unsigned short* bcur = bufA;
    unsigned short* bnxt = bufB;

    for (int it = 0; it < ntiles; ++it) {
        const bool pf = (it + 1 < ntiles);
        if (pf) {  // issue next tile's loads NOW; latency hides under compute
            const int nx = (it + 1) * 64;
            kr0 = *(const bf16x8*)(Kg + (size_t)(nx + rlo) * 3072 + c8);
            kr1 = *(const bf16x8*)(Kg + (size_t)(nx + rlo + 32) * 3072 + c8);
            vr0 = *(const bf16x8*)(Vg + (size_t)rlo * 2048 + nx + c8);
            vr1 = *(const bf16x8*)(Vg + (size_t)(rlo + 32) * 2048 + nx + c8);
        }

        const unsigned short* sK = bcur;
        const unsigned short* sV = bcur + 64 * 72;

        // K A-fragments (permuted rows): ka[f][half] covers d half 0/1.
        bf16x8 ka[2][2];
#pragma unroll
        for (int f = 0; f < 2; ++f) {
            ka[f][0] = *(const bf16x8*)&sK[(krow0 + 4 * f) * 72 + quad * 8];
            ka[f][1] = *(const bf16x8*)&sK[(krow0 + 4 * f) * 72 + 32 + quad * 8];
        }
        // V B-fragments: vb[nt] = Vt[d=nt*16+l16][kv = kvh*32 + quad*8 + j]
        bf16x8 vb[4];
#pragma unroll
        for (int nt = 0; nt < 4; ++nt)
            vb[nt] = *(const bf16x8*)&sV[(nt * 16 + l16) * 72 + kvh * 32 + quad * 8];

        const int kv0 = it * 64;
        const bool diag = (it == qblk);
#pragma unroll
        for (int m = 0; m < 2; ++m) {
            const int qa = q0 + m * 16 + l16;  // absolute q for this thread
            unsigned int pw[4];
            float lsum = 0.f;
#pragma unroll
            for (int f = 0; f < 2; ++f) {
                f32x4 S = (f32x4){0.f, 0.f, 0.f, 0.f};
                S = __builtin_amdgcn_mfma_f32_16x16x32_bf16(ka[f][0], qf[m][0], S, 0, 0, 0);
                S = __builtin_amdgcn_mfma_f32_16x16x32_bf16(ka[f][1], qf[m][1], S, 0, 0, 0);
                float p0, p1, p2, p3;
                {
                    float sv = S[0] * csc;
                    asm("v_exp_f32 %0, %1" : "=v"(p0) : "v"(sv));
                    sv = S[1] * csc;
                    asm("v_exp_f32 %0, %1" : "=v"(p1) : "v"(sv));
                    sv = S[2] * csc;
                    asm("v_exp_f32 %0, %1" : "=v"(p2) : "v"(sv));
                    sv = S[3] * csc;
                    asm("v_exp_f32 %0, %1" : "=v"(p3) : "v"(sv));
                }
                if (diag) {  // kv_abs = kv0 + kvh*32 + 8*quad + 4f + r
                    int kvb = kv0 + kvh * 32 + 8 * quad + 4 * f;
                    p0 = (kvb + 0 <= qa) ? p0 : 0.f;
                    p1 = (kvb + 1 <= qa) ? p1 : 0.f;
                    p2 = (kvb + 2 <= qa) ? p2 : 0.f;
                    p3 = (kvb + 3 <= qa) ? p3 : 0.f;
                }
                lsum += (p0 + p1) + (p2 + p3);
                asm("v_cvt_pk_bf16_f32 %0, %1, %2" : "=v"(pw[f * 2 + 0]) : "v"(p0), "v"(p1));
                asm("v_cvt_pk_bf16_f32 %0, %1, %2" : "=v"(pw[f * 2 + 1]) : "v"(p2), "v"(p3));
            }
            lacc[m] += lsum;
            union {
                unsigned int u[4];
                bf16x8 v;
            } pa;
            pa.u[0] = pw[0]; pa.u[1] = pw[1]; pa.u[2] = pw[2]; pa.u[3] = pw[3];
#pragma unroll
            for (int nt = 0; nt < 4; ++nt)
                o[m][nt] = __builtin_amdgcn_mfma_f32_16x16x32_bf16(
                    pa.v, vb[nt], o[m][nt], 0, 0, 0);
        }

        if (pf) {  // write prefetched tile to the other buffer (vmcnt waits here)
            unsigned short* dK = bnxt;
            unsigned short* dV = bnxt + 64 * 72;
            *(bf16x8*)&dK[rlo * 72 + c8] = kr0;
            *(bf16x8*)&dK[(rlo + 32) * 72 + c8] = kr1;
            *(bf16x8*)&dV[rlo * 72 + c8] = vr0;
            *(bf16x8*)&dV[(rlo + 32) * 72 + c8] = vr1;
        }
        __syncthreads();  // single barrier: RAW for bnxt, WAR for bcur
        unsigned short* t = bcur; bcur = bnxt; bnxt = t;
    }

    // Per-wave denom: sum over quads (kv within the wave's half).
#pragma unroll
    for (int m = 0; m < 2; ++m) {
        lacc[m] += __shfl_xor(lacc[m], 16);
        lacc[m] += __shfl_xor(lacc[m], 32);
    }

    // Last loop barrier already separates main-loop LDS use from reuse below.
    if (kvh == 1) {   // kv-half 1 waves publish partial o
        float* dst = sO + qh * (64 * 36);
#pragma unroll
        for (int m = 0; m < 2; ++m)
#pragma unroll
            for (int nt = 0; nt < 4; ++nt)
                *(f32x4*)&dst[(nt * 16 + l16) * 36 + m * 16 + quad * 4] = o[m][nt];
    }
    if (lane < 16) {
        sD[w * 32 + l16] = lacc[0];
        sD[w * 32 + 16 + l16] = lacc[1];
    }
    __syncthreads();
    if (kvh == 0) {  // kv-half 0 waves combine and write output
        const float* src = sO + qh * (64 * 36);
        unsigned short* yb = y + (size_t)(b * 2048) * 1024 + h * 64;
#pragma unroll
        for (int m = 0; m < 2; ++m) {
            float dfull = lacc[m] + sD[(w + 2) * 32 + m * 16 + l16];
            float lt[4];
#pragma unroll
            for (int r = 0; r < 4; ++r) lt[r] = __shfl(dfull, quad * 4 + r);
#pragma unroll
            for (int nt = 0; nt < 4; ++nt) {
                f32x4 part = *(const f32x4*)&src[(nt * 16 + l16) * 36 + m * 16 + quad * 4];
#pragma unroll
                for (int r = 0; r < 4; ++r)
                    yb[(size_t)(q0 + m * 16 + quad * 4 + r) * 1024 + nt * 16 + l16] =
                        f2bf((o[m][nt][r] + part[r]) / lt[r]);
            }
        }
    }
}

// -------------------------------------------------------------------------
extern "C" void kernel_launch(void* const* d_in, const int* in_sizes, int n_in,
                              void* d_out, int out_size, void* d_ws, size_t ws_size,
                              hipStream_t stream) {
    const float* x       = (const float*)d_in[0];
    const float* w_attn  = (const float*)d_in[1];
    const float* b_attn  = (const float*)d_in[2];
    const float* la_attn = (const float*)d_in[3];
    const float* lb_attn = (const float*)d_in[4];
    const float* w_proj  = (const float*)d_in[5];
    const float* b_proj  = (const float*)d_in[6];
    const float* la_proj = (const float*)d_in[7];
    const float* lb_proj = (const float*)d_in[8];
    float* out = (float*)d_out;

    char* w = (char*)d_ws;
    unsigned short* xb        = (unsigned short*)w; w += (size_t)4096 * 1024 * 2;
    unsigned short* Weff_attn = (unsigned short*)w; w += (size_t)3072 * 1024 * 2;
    unsigned short* Weff_proj = (unsigned short*)w; w += (size_t)1024 * 1024 * 2;
    unsigned short* qkv       = (unsigned short*)w; w += (size_t)4096 * 3072 * 2;
    unsigned short* Vt        = (unsigned short*)w; w += (size_t)32 * 64 * 2048 * 2;
    unsigned short* y         = (unsigned short*)w; w += (size_t)4096 * 1024 * 2;

    prep<<<4096, 256, 0, stream>>>(x, xb, w_attn, la_attn, lb_attn, Weff_attn,
                                   w_proj, la_proj, lb_proj, Weff_proj);
    gemm_bt_bias<false, true><<<dim3(24, 32), 256, 0, stream>>>(
        xb, Weff_attn, b_attn, qkv, (float*)nullptr, Vt, 4096, 3072, 1024);
    attn_kernel<<<dim3(32, 16, 2), 256, 0, stream>>>(qkv, Vt, y);
    gemm_bt_bias64<<<dim3(8, 64), 256, 0, stream>>>(
        y, Weff_proj, b_proj, out, 4096, 1024, 1024);
}